// Round 1
// baseline (266.287 us; speedup 1.0000x reference)
//
#include <hip/hip_runtime.h>

#define BATCH 8
#define ROWS 1536
#define NCOLS 16
#define KCLS 32
#define NTOT (BATCH*ROWS)        // 12288
#define ELEMS (NTOT*NCOLS)       // 196608

// workspace layout (float offsets)
enum : int {
  WS_Z     = 0,                      // [8][1536][16]
  WS_CPART = WS_Z + NTOT*16,         // [8][6][512]
  WS_CENT  = WS_CPART + BATCH*6*512, // [8][32*16]
  WS_D2    = WS_CENT + BATCH*512,    // [8][1536]
  WS_D2MM  = WS_D2 + NTOT,           // [48][2]
  WS_X     = WS_D2MM + 96,           // [8][1536]  (scaled/eps)
  WS_XS    = WS_X + NTOT,            // [8][1536]  (desc-sorted x)
  WS_S     = WS_XS + NTOT,           // [8][1537]  prefix sums
  WS_DESC  = WS_S + BATCH*(ROWS+1),  // [8][1536]  int
  WS_LOSSP = WS_DESC + NTOT,         // [48]
};

// ---------------- K1: autoencoder, z, per-block loss partials ----------------
__global__ __launch_bounds__(256) void k1_ae(
    const float* __restrict__ table,
    const float* __restrict__ w1, const float* __restrict__ b1,
    const float* __restrict__ w2, const float* __restrict__ b2,
    const float* __restrict__ mw, const float* __restrict__ mb,
    const float* __restrict__ dw1, const float* __restrict__ db1,
    const float* __restrict__ dw2, const float* __restrict__ db2,
    float* __restrict__ ws)
{
  const int row = blockIdx.x * 256 + threadIdx.x; // 0..12287
  float x[16];
  {
    const float4* tp = reinterpret_cast<const float4*>(table + row * 16);
    float4 a0 = tp[0], a1 = tp[1], a2 = tp[2], a3 = tp[3];
    x[0]=a0.x; x[1]=a0.y; x[2]=a0.z; x[3]=a0.w;
    x[4]=a1.x; x[5]=a1.y; x[6]=a1.z; x[7]=a1.w;
    x[8]=a2.x; x[9]=a2.y; x[10]=a2.z; x[11]=a2.w;
    x[12]=a3.x; x[13]=a3.y; x[14]=a3.z; x[15]=a3.w;
  }
  float h1[32];
#pragma unroll
  for (int j = 0; j < 32; ++j) h1[j] = b1[j];
#pragma unroll
  for (int i = 0; i < 16; ++i) {
    const float xi = x[i];
#pragma unroll
    for (int j = 0; j < 32; ++j) h1[j] = fmaf(xi, w1[i*32 + j], h1[j]);
  }
#pragma unroll
  for (int j = 0; j < 32; ++j) h1[j] = fmaxf(h1[j], 0.f);

  float h2[64];
#pragma unroll
  for (int j = 0; j < 64; ++j) h2[j] = b2[j];
#pragma unroll
  for (int i = 0; i < 32; ++i) {
    const float hi = h1[i];
#pragma unroll
    for (int j = 0; j < 64; ++j) h2[j] = fmaf(hi, w2[i*64 + j], h2[j]);
  }
#pragma unroll
  for (int j = 0; j < 64; ++j) h2[j] = fmaxf(h2[j], 0.f);

  float z[16];
#pragma unroll
  for (int j = 0; j < 16; ++j) z[j] = mb[j];
#pragma unroll
  for (int i = 0; i < 64; ++i) {
    const float hi = h2[i];
#pragma unroll
    for (int j = 0; j < 16; ++j) z[j] = fmaf(hi, mw[i*16 + j], z[j]);
  }
  {
    float4* zp = reinterpret_cast<float4*>(ws + WS_Z + row * 16);
    zp[0] = make_float4(z[0], z[1], z[2], z[3]);
    zp[1] = make_float4(z[4], z[5], z[6], z[7]);
    zp[2] = make_float4(z[8], z[9], z[10], z[11]);
    zp[3] = make_float4(z[12], z[13], z[14], z[15]);
  }
  float r1[32];
#pragma unroll
  for (int j = 0; j < 32; ++j) r1[j] = db1[j];
#pragma unroll
  for (int i = 0; i < 16; ++i) {
    const float zi = z[i];
#pragma unroll
    for (int j = 0; j < 32; ++j) r1[j] = fmaf(zi, dw1[i*32 + j], r1[j]);
  }
#pragma unroll
  for (int j = 0; j < 32; ++j) r1[j] = fmaxf(r1[j], 0.f);

  float rec[16];
#pragma unroll
  for (int j = 0; j < 16; ++j) rec[j] = db2[j];
#pragma unroll
  for (int i = 0; i < 32; ++i) {
    const float ri = r1[i];
#pragma unroll
    for (int j = 0; j < 16; ++j) rec[j] = fmaf(ri, dw2[i*16 + j], rec[j]);
  }
  float ls = 0.f;
#pragma unroll
  for (int j = 0; j < 16; ++j) {
    float d = fmaxf(rec[j], 0.f) - x[j];
    ls = fmaf(d, d, ls);
  }
  // block loss reduction (deterministic tree)
  for (int off = 32; off > 0; off >>= 1) ls += __shfl_down(ls, off);
  __shared__ float wred[4];
  const int lane = threadIdx.x & 63, wv = threadIdx.x >> 6;
  if (lane == 0) wred[wv] = ls;
  __syncthreads();
  if (threadIdx.x == 0)
    ws[WS_LOSSP + blockIdx.x] = (wred[0] + wred[1]) + (wred[2] + wred[3]);
}

// ---------------- K2: partial center sums over 256-row chunks ----------------
__global__ __launch_bounds__(512) void k2_cpart(const int* __restrict__ labels,
                                                float* __restrict__ ws)
{
  const int b = blockIdx.x / 6, ch = blockIdx.x % 6;
  __shared__ int lbl[256];
  if (threadIdx.x < 256) lbl[threadIdx.x] = labels[ch*256 + threadIdx.x];
  __syncthreads();
  const int k = threadIdx.x >> 4, d = threadIdx.x & 15;
  const float* zb = ws + WS_Z + (b*ROWS + ch*256) * 16;
  float acc = 0.f;
  for (int rr = 0; rr < 256; ++rr) {
    float zv = zb[rr*16 + d];
    acc += (lbl[rr] == k) ? zv : 0.f;
  }
  ws[WS_CPART + (b*6 + ch)*512 + threadIdx.x] = acc;
}

// ---------------- K3: finalize centers (+ counts) and loss ----------------
__global__ __launch_bounds__(512) void k3_cfinal(const int* __restrict__ labels,
                                                 float* __restrict__ ws,
                                                 float* __restrict__ out)
{
  const int b = blockIdx.x;
  __shared__ int cnt[KCLS];
  if (threadIdx.x < KCLS) cnt[threadIdx.x] = 0;
  __syncthreads();
  for (int t = threadIdx.x; t < ROWS; t += 512) atomicAdd(&cnt[labels[t]], 1);
  __syncthreads();
  float s = 0.f;
#pragma unroll
  for (int c = 0; c < 6; ++c) s += ws[WS_CPART + (b*6 + c)*512 + threadIdx.x];
  const int k = threadIdx.x >> 4;
  const int cn = cnt[k] > 1 ? cnt[k] : 1;
  ws[WS_CENT + b*512 + threadIdx.x] = s / (float)cn;
  if (b == 0 && threadIdx.x == 0) {
    float L = 0.f;
    for (int i = 0; i < 48; ++i) L += ws[WS_LOSSP + i];
    out[3*NTOT] = L / (float)ELEMS;
  }
}

// ---------------- K4: d2 + per-block min/max partials ----------------
__global__ __launch_bounds__(256) void k4_d2(const int* __restrict__ labels,
                                             float* __restrict__ ws)
{
  const int row = blockIdx.x*256 + threadIdx.x;
  const int b = row / ROWS, r = row % ROWS;
  const int lbl = labels[r];
  const float4* zp = reinterpret_cast<const float4*>(ws + WS_Z + row*16);
  const float4* cp = reinterpret_cast<const float4*>(ws + WS_CENT + b*512 + lbl*16);
  float s = 0.f;
#pragma unroll
  for (int q = 0; q < 4; ++q) {
    float4 zv = zp[q], cv = cp[q];
    float d0 = zv.x - cv.x, d1 = zv.y - cv.y, d2_ = zv.z - cv.z, d3 = zv.w - cv.w;
    s += d0*d0 + d1*d1 + d2_*d2_ + d3*d3;
  }
  const float d2v = s / 16.f;
  ws[WS_D2 + row] = d2v;
  __shared__ float rmn[256], rmx[256];
  rmn[threadIdx.x] = d2v; rmx[threadIdx.x] = d2v;
  __syncthreads();
  for (int off = 128; off > 0; off >>= 1) {
    if (threadIdx.x < off) {
      rmn[threadIdx.x] = fminf(rmn[threadIdx.x], rmn[threadIdx.x + off]);
      rmx[threadIdx.x] = fmaxf(rmx[threadIdx.x], rmx[threadIdx.x + off]);
    }
    __syncthreads();
  }
  if (threadIdx.x == 0) {
    ws[WS_D2MM + blockIdx.x*2]     = rmn[0];
    ws[WS_D2MM + blockIdx.x*2 + 1] = rmx[0];
  }
}

// ---------------- K5: scores + scaled (x = scaled/eps) ----------------
__global__ __launch_bounds__(256) void k5_scores(const int* __restrict__ labels,
                                                 float* __restrict__ ws,
                                                 float* __restrict__ out)
{
  const int b = blockIdx.x;
  float mn = 3.0e38f, mx = -3.0e38f;
#pragma unroll
  for (int c = 0; c < 6; ++c) {
    mn = fminf(mn, ws[WS_D2MM + (b*6 + c)*2]);
    mx = fmaxf(mx, ws[WS_D2MM + (b*6 + c)*2 + 1]);
  }
  float svals[6];
  float tmn = 3.0e38f, tmx = -3.0e38f;
#pragma unroll
  for (int c = 0; c < 6; ++c) {
    const int r = c*256 + threadIdx.x;
    float v = (ws[WS_D2 + b*ROWS + r] - mn) / (mx - mn);
    float sc = v + (float)labels[r];
    svals[c] = sc;
    out[2*NTOT + b*ROWS + r] = sc;
    tmn = fminf(tmn, sc); tmx = fmaxf(tmx, sc);
  }
  __shared__ float rmn[256], rmx[256];
  rmn[threadIdx.x] = tmn; rmx[threadIdx.x] = tmx;
  __syncthreads();
  for (int off = 128; off > 0; off >>= 1) {
    if (threadIdx.x < off) {
      rmn[threadIdx.x] = fminf(rmn[threadIdx.x], rmn[threadIdx.x + off]);
      rmx[threadIdx.x] = fmaxf(rmx[threadIdx.x], rmx[threadIdx.x + off]);
    }
    __syncthreads();
  }
  const float smn = rmn[0], smx = rmx[0];
#pragma unroll
  for (int c = 0; c < 6; ++c) {
    const int r = c*256 + threadIdx.x;
    float scl = (svals[c] - smn) / (smx - smn) * 8.0f;
    ws[WS_X + b*ROWS + r] = scl / 0.01f;
  }
}

// ---------------- K6: stable rank counting (asc on scores, desc on x) --------
__global__ __launch_bounds__(768) void k6_rank(const int* __restrict__ bsp,
                                               float* __restrict__ ws,
                                               float* __restrict__ out)
{
  const int b = blockIdx.x >> 1, half = blockIdx.x & 1;
  __shared__ float s_l[ROWS], x_l[ROWS];
  for (int t = threadIdx.x; t < ROWS; t += 768) {
    s_l[t] = out[2*NTOT + b*ROWS + t];
    x_l[t] = ws[WS_X + b*ROWS + t];
  }
  __syncthreads();
  const int r = half*768 + threadIdx.x;
  const float si = s_l[r], xi = x_l[r];
  int asc = 0, dsc = 0;
#pragma unroll 4
  for (int j = 0; j < ROWS; ++j) {
    const float sj = s_l[j], xj = x_l[j];
    asc += (sj < si || (sj == si && j < r)) ? 1 : 0;
    dsc += (xj > xi || (xj == xi && j < r)) ? 1 : 0;
  }
  const int BS = *bsp;
  out[NTOT + b*ROWS + r] = (float)(asc / BS + 1);
  reinterpret_cast<int*>(ws)[WS_DESC + b*ROWS + r] = dsc;
  ws[WS_XS + b*ROWS + dsc] = xi;   // scatter: xs in descending order
}

// ---------------- K7: prefix sums S of y = w - xs ----------------
__global__ __launch_bounds__(256) void k7_scan(float* __restrict__ ws)
{
  const int b = blockIdx.x;
  const float* xs = ws + WS_XS + b*ROWS;
  const int base = threadIdx.x * 6;
  float y[6];
  float sum = 0.f;
#pragma unroll
  for (int u = 0; u < 6; ++u) {
    y[u] = (float)(ROWS - (base + u)) - xs[base + u];
    sum += y[u];
  }
  __shared__ float ts[256];
  ts[threadIdx.x] = sum;
  __syncthreads();
  for (int off = 1; off < 256; off <<= 1) {
    float v = ts[threadIdx.x];
    if (threadIdx.x >= off) v += ts[threadIdx.x - off];
    __syncthreads();
    ts[threadIdx.x] = v;
    __syncthreads();
  }
  float run = threadIdx.x ? ts[threadIdx.x - 1] : 0.f;
  float* S = ws + WS_S + b*(ROWS + 1);
#pragma unroll
  for (int u = 0; u < 6; ++u) { S[base + u] = run; run += y[u]; }
  if (threadIdx.x == 255) S[ROWS] = run;
}

// ---------------- K8: isotonic regression (minimax) + ranks ----------------
__global__ __launch_bounds__(768) void k8_iso(float* __restrict__ ws,
                                              float* __restrict__ out)
{
  const int b = blockIdx.x;
  __shared__ float S[ROWS + 1], inv[ROWS + 1], g[ROWS], pm[768];
  for (int t = threadIdx.x; t <= ROWS; t += 768) {
    S[t] = ws[WS_S + b*(ROWS + 1) + t];
    inv[t] = (t > 0) ? 1.0f / (float)t : 0.f;
  }
  __syncthreads();
  // g[i] = min_{len>=1} (S[i+len]-S[i]) / len ; balanced pairing i and n-1-i
  {
    const int i = threadIdx.x;
    const float Si = S[i];
    float gm = 3.0e38f;
#pragma unroll 4
    for (int s2 = 0; s2 < ROWS - i; ++s2)
      gm = fminf(gm, (S[i + 1 + s2] - Si) * inv[s2 + 1]);
    g[i] = gm;
  }
  {
    const int i = ROWS - 1 - threadIdx.x;
    const float Si = S[i];
    float gm = 3.0e38f;
#pragma unroll 4
    for (int s2 = 0; s2 < ROWS - i; ++s2)
      gm = fminf(gm, (S[i + 1 + s2] - Si) * inv[s2 + 1]);
    g[i] = gm;
  }
  __syncthreads();
  // inclusive prefix-max of g (exact; max is rounding-free)
  const float a = g[2*threadIdx.x], c = g[2*threadIdx.x + 1];
  pm[threadIdx.x] = fmaxf(a, c);
  __syncthreads();
  for (int off = 1; off < 768; off <<= 1) {
    float v = pm[threadIdx.x];
    if (threadIdx.x >= off) v = fmaxf(v, pm[threadIdx.x - off]);
    __syncthreads();
    pm[threadIdx.x] = v;
    __syncthreads();
  }
  const float excl = threadIdx.x ? pm[threadIdx.x - 1] : -3.0e38f;
  const float i0 = fmaxf(excl, a);
  const float i1 = fmaxf(i0, c);
  g[2*threadIdx.x] = i0; g[2*threadIdx.x + 1] = i1;
  __syncthreads();
  // ranks[orig] = xs[desc_rank[orig]] + iso[desc_rank[orig]]
  const float* xs = ws + WS_XS + b*ROWS;
  const int* desc = reinterpret_cast<const int*>(ws) + WS_DESC + b*ROWS;
  for (int t = threadIdx.x; t < ROWS; t += 768) {
    const int dr = desc[t];
    out[b*ROWS + t] = xs[dr] + g[dr];
  }
}

extern "C" void kernel_launch(void* const* d_in, const int* in_sizes, int n_in,
                              void* d_out, int out_size, void* d_ws, size_t ws_size,
                              hipStream_t stream) {
  const float* table = (const float*)d_in[0];
  const float* w1  = (const float*)d_in[1];
  const float* b1  = (const float*)d_in[2];
  const float* w2  = (const float*)d_in[3];
  const float* b2  = (const float*)d_in[4];
  const float* mw  = (const float*)d_in[5];
  const float* mb  = (const float*)d_in[6];
  const float* dw1 = (const float*)d_in[7];
  const float* db1 = (const float*)d_in[8];
  const float* dw2 = (const float*)d_in[9];
  const float* db2 = (const float*)d_in[10];
  const int* labels = (const int*)d_in[11];
  const int* bsp    = (const int*)d_in[12];
  float* out = (float*)d_out;
  float* ws  = (float*)d_ws;

  k1_ae<<<48, 256, 0, stream>>>(table, w1, b1, w2, b2, mw, mb, dw1, db1, dw2, db2, ws);
  k2_cpart<<<48, 512, 0, stream>>>(labels, ws);
  k3_cfinal<<<8, 512, 0, stream>>>(labels, ws, out);
  k4_d2<<<48, 256, 0, stream>>>(labels, ws);
  k5_scores<<<8, 256, 0, stream>>>(labels, ws, out);
  k6_rank<<<16, 768, 0, stream>>>(bsp, ws, out);
  k7_scan<<<8, 256, 0, stream>>>(ws);
  k8_iso<<<8, 768, 0, stream>>>(ws, out);
}

// Round 2
// 86.545 us; speedup vs baseline: 3.0769x; 3.0769x over previous
//
#include <hip/hip_runtime.h>

#define BATCH 8
#define ROWS 1536
#define KCLS 32
#define NTOT (BATCH*ROWS)        // 12288
#define ELEMS (NTOT*16)          // 196608
#define SSTRIDE 3073             // padded prefix-sum stride per batch
#define BIGF 1.0e30f

// workspace layout (float offsets)
enum : int {
  WS_Z     = 0,                          // [8][1536][16]
  WS_CPART = WS_Z + NTOT*16,             // [8][6][512]
  WS_X     = WS_CPART + BATCH*6*512,     // [8][1536]
  WS_XS    = WS_X + NTOT,                // [8][1536]
  WS_S     = WS_XS + NTOT,               // [8][3073] padded
  WS_DESC  = WS_S + BATCH*SSTRIDE,       // [8][1536] int
  WS_ASCP  = WS_DESC + NTOT,             // [4][12288] int
  WS_DSCP  = WS_ASCP + 4*NTOT,           // [4][12288] int
  WS_GPART = WS_DSCP + 4*NTOT,           // [8][8][1536]
  WS_LOSSP = WS_GPART + BATCH*8*ROWS,    // [96]
};

// ---------------- K1: autoencoder, z, per-block loss partials ----------------
__global__ __launch_bounds__(128) void k1_ae(
    const float* __restrict__ table,
    const float* __restrict__ w1, const float* __restrict__ b1,
    const float* __restrict__ w2, const float* __restrict__ b2,
    const float* __restrict__ mw, const float* __restrict__ mb,
    const float* __restrict__ dw1, const float* __restrict__ db1,
    const float* __restrict__ dw2, const float* __restrict__ db2,
    float* __restrict__ ws)
{
  const int row = blockIdx.x * 128 + threadIdx.x; // 0..12287
  float x[16];
  {
    const float4* tp = reinterpret_cast<const float4*>(table + row * 16);
    float4 a0 = tp[0], a1 = tp[1], a2 = tp[2], a3 = tp[3];
    x[0]=a0.x; x[1]=a0.y; x[2]=a0.z; x[3]=a0.w;
    x[4]=a1.x; x[5]=a1.y; x[6]=a1.z; x[7]=a1.w;
    x[8]=a2.x; x[9]=a2.y; x[10]=a2.z; x[11]=a2.w;
    x[12]=a3.x; x[13]=a3.y; x[14]=a3.z; x[15]=a3.w;
  }
  float h1[32];
#pragma unroll
  for (int j = 0; j < 32; ++j) h1[j] = b1[j];
#pragma unroll
  for (int i = 0; i < 16; ++i) {
    const float xi = x[i];
#pragma unroll
    for (int j = 0; j < 32; ++j) h1[j] = fmaf(xi, w1[i*32 + j], h1[j]);
  }
#pragma unroll
  for (int j = 0; j < 32; ++j) h1[j] = fmaxf(h1[j], 0.f);

  float h2[64];
#pragma unroll
  for (int j = 0; j < 64; ++j) h2[j] = b2[j];
#pragma unroll
  for (int i = 0; i < 32; ++i) {
    const float hi = h1[i];
#pragma unroll
    for (int j = 0; j < 64; ++j) h2[j] = fmaf(hi, w2[i*64 + j], h2[j]);
  }
#pragma unroll
  for (int j = 0; j < 64; ++j) h2[j] = fmaxf(h2[j], 0.f);

  float z[16];
#pragma unroll
  for (int j = 0; j < 16; ++j) z[j] = mb[j];
#pragma unroll
  for (int i = 0; i < 64; ++i) {
    const float hi = h2[i];
#pragma unroll
    for (int j = 0; j < 16; ++j) z[j] = fmaf(hi, mw[i*16 + j], z[j]);
  }
  {
    float4* zp = reinterpret_cast<float4*>(ws + WS_Z + row * 16);
    zp[0] = make_float4(z[0], z[1], z[2], z[3]);
    zp[1] = make_float4(z[4], z[5], z[6], z[7]);
    zp[2] = make_float4(z[8], z[9], z[10], z[11]);
    zp[3] = make_float4(z[12], z[13], z[14], z[15]);
  }
  float r1[32];
#pragma unroll
  for (int j = 0; j < 32; ++j) r1[j] = db1[j];
#pragma unroll
  for (int i = 0; i < 16; ++i) {
    const float zi = z[i];
#pragma unroll
    for (int j = 0; j < 32; ++j) r1[j] = fmaf(zi, dw1[i*32 + j], r1[j]);
  }
#pragma unroll
  for (int j = 0; j < 32; ++j) r1[j] = fmaxf(r1[j], 0.f);

  float rec[16];
#pragma unroll
  for (int j = 0; j < 16; ++j) rec[j] = db2[j];
#pragma unroll
  for (int i = 0; i < 32; ++i) {
    const float ri = r1[i];
#pragma unroll
    for (int j = 0; j < 16; ++j) rec[j] = fmaf(ri, dw2[i*16 + j], rec[j]);
  }
  float ls = 0.f;
#pragma unroll
  for (int j = 0; j < 16; ++j) {
    float d = fmaxf(rec[j], 0.f) - x[j];
    ls = fmaf(d, d, ls);
  }
  for (int off = 32; off > 0; off >>= 1) ls += __shfl_down(ls, off);
  __shared__ float wred[2];
  const int lane = threadIdx.x & 63, wv = threadIdx.x >> 6;
  if (lane == 0) wred[wv] = ls;
  __syncthreads();
  if (threadIdx.x == 0) ws[WS_LOSSP + blockIdx.x] = wred[0] + wred[1];
}

// ---------------- K2: partial center sums over 256-row chunks ----------------
__global__ __launch_bounds__(512) void k2_cpart(const int* __restrict__ labels,
                                                float* __restrict__ ws)
{
  const int b = blockIdx.x / 6, ch = blockIdx.x % 6;
  __shared__ int lbl[256];
  if (threadIdx.x < 256) lbl[threadIdx.x] = labels[ch*256 + threadIdx.x];
  __syncthreads();
  const int k = threadIdx.x >> 4, d = threadIdx.x & 15;
  const float* zb = ws + WS_Z + (b*ROWS + ch*256) * 16;
  float acc = 0.f;
  for (int rr = 0; rr < 256; ++rr) {
    float zv = zb[rr*16 + d];
    acc += (lbl[rr] == k) ? zv : 0.f;
  }
  ws[WS_CPART + (b*6 + ch)*512 + threadIdx.x] = acc;
}

// ---- K345: centers finalize + loss + d2 + normalizations + scores + x ------
__global__ __launch_bounds__(256) void k345(const int* __restrict__ labels,
                                            float* __restrict__ ws,
                                            float* __restrict__ out)
{
  const int b = blockIdx.x;
  const int tid = threadIdx.x;
  __shared__ int cnt[KCLS];
  __shared__ float cent[512];
  __shared__ float rmn[256], rmx[256];
  __shared__ int lbl_l[ROWS];

  if (tid < KCLS) cnt[tid] = 0;
  __syncthreads();
#pragma unroll
  for (int c = 0; c < 6; ++c) {
    int lb = labels[c*256 + tid];
    lbl_l[c*256 + tid] = lb;
    atomicAdd(&cnt[lb], 1);
  }
  __syncthreads();
#pragma unroll
  for (int e = tid; e < 512; e += 256) {
    float s = 0.f;
#pragma unroll
    for (int c = 0; c < 6; ++c) s += ws[WS_CPART + (b*6 + c)*512 + e];
    const int cn = cnt[e >> 4] > 1 ? cnt[e >> 4] : 1;
    cent[e] = s / (float)cn;
  }
  if (b == 0 && tid == 0) {
    float L = 0.f;
    for (int i = 0; i < 96; ++i) L += ws[WS_LOSSP + i];
    out[3*NTOT] = L / (float)ELEMS;
  }
  __syncthreads();

  // d2 per row (6 rows/thread), block min/max
  float d2v[6];
  float tmn = 3.0e38f, tmx = -3.0e38f;
#pragma unroll
  for (int c = 0; c < 6; ++c) {
    const int r = c*256 + tid;
    const int lb = lbl_l[r];
    const float4* zp = reinterpret_cast<const float4*>(ws + WS_Z + (b*ROWS + r)*16);
    const float4* cp = reinterpret_cast<const float4*>(&cent[lb*16]);
    float s = 0.f;
#pragma unroll
    for (int q = 0; q < 4; ++q) {
      float4 zv = zp[q], cv = cp[q];
      float d0 = zv.x - cv.x, d1 = zv.y - cv.y, d2_ = zv.z - cv.z, d3 = zv.w - cv.w;
      s += d0*d0 + d1*d1 + d2_*d2_ + d3*d3;
    }
    d2v[c] = s / 16.f;
    tmn = fminf(tmn, d2v[c]); tmx = fmaxf(tmx, d2v[c]);
  }
  rmn[tid] = tmn; rmx[tid] = tmx;
  __syncthreads();
  for (int off = 128; off > 0; off >>= 1) {
    if (tid < off) {
      rmn[tid] = fminf(rmn[tid], rmn[tid + off]);
      rmx[tid] = fmaxf(rmx[tid], rmx[tid + off]);
    }
    __syncthreads();
  }
  const float mn = rmn[0], mx = rmx[0];
  __syncthreads();

  float sv[6];
  tmn = 3.0e38f; tmx = -3.0e38f;
#pragma unroll
  for (int c = 0; c < 6; ++c) {
    const int r = c*256 + tid;
    float sc = (d2v[c] - mn) / (mx - mn) + (float)lbl_l[r];
    sv[c] = sc;
    out[2*NTOT + b*ROWS + r] = sc;
    tmn = fminf(tmn, sc); tmx = fmaxf(tmx, sc);
  }
  rmn[tid] = tmn; rmx[tid] = tmx;
  __syncthreads();
  for (int off = 128; off > 0; off >>= 1) {
    if (tid < off) {
      rmn[tid] = fminf(rmn[tid], rmn[tid + off]);
      rmx[tid] = fmaxf(rmx[tid], rmx[tid + off]);
    }
    __syncthreads();
  }
  const float smn = rmn[0], smx = rmx[0];
#pragma unroll
  for (int c = 0; c < 6; ++c) {
    const int r = c*256 + tid;
    float scl = (sv[c] - smn) / (smx - smn) * 8.0f;
    ws[WS_X + b*ROWS + r] = scl / 0.01f;
  }
}

// ---------------- K6: partial stable rank counts (192 blocks) ----------------
__global__ __launch_bounds__(256) void k6_count(float* __restrict__ ws,
                                                const float* __restrict__ out)
{
  const int bi = blockIdx.x;
  const int jb = bi & 3, rb = (bi >> 2) % 6, b = bi / 24;
  const int tid = threadIdx.x;
  __shared__ float4 sld[96], xld[96];
  {
    float* sf = reinterpret_cast<float*>(sld);
    float* xf = reinterpret_cast<float*>(xld);
    const int base = b*ROWS + jb*384;
    sf[tid] = out[2*NTOT + base + tid];
    xf[tid] = ws[WS_X + base + tid];
    if (tid < 128) {
      sf[256 + tid] = out[2*NTOT + base + 256 + tid];
      xf[256 + tid] = ws[WS_X + base + 256 + tid];
    }
  }
  __syncthreads();
  const int r = rb*256 + tid;
  const float si = out[2*NTOT + b*ROWS + r];
  const float xi = ws[WS_X + b*ROWS + r];
  int asc = 0, dsc = 0;
  const int j0 = jb*384;
#pragma unroll 4
  for (int kk = 0; kk < 96; ++kk) {
    const float4 s4 = sld[kk];
    const float4 x4 = xld[kk];
    const int j = j0 + kk*4;
    asc += (s4.x < si || (s4.x == si && j   < r)) ? 1 : 0;
    asc += (s4.y < si || (s4.y == si && j+1 < r)) ? 1 : 0;
    asc += (s4.z < si || (s4.z == si && j+2 < r)) ? 1 : 0;
    asc += (s4.w < si || (s4.w == si && j+3 < r)) ? 1 : 0;
    dsc += (x4.x > xi || (x4.x == xi && j   < r)) ? 1 : 0;
    dsc += (x4.y > xi || (x4.y == xi && j+1 < r)) ? 1 : 0;
    dsc += (x4.z > xi || (x4.z == xi && j+2 < r)) ? 1 : 0;
    dsc += (x4.w > xi || (x4.w == xi && j+3 < r)) ? 1 : 0;
  }
  int* wsi = reinterpret_cast<int*>(ws);
  wsi[WS_ASCP + jb*NTOT + b*ROWS + r] = asc;
  wsi[WS_DSCP + jb*NTOT + b*ROWS + r] = dsc;
}

// ------- K67: finalize counts -> rank_idx, scatter xs, prefix-sum S ---------
__global__ __launch_bounds__(256) void k67(const int* __restrict__ bsp,
                                           float* __restrict__ ws,
                                           float* __restrict__ out)
{
  const int b = blockIdx.x, tid = threadIdx.x;
  __shared__ float xs_l[ROWS];
  __shared__ float ts[256];
  const int* wsi = reinterpret_cast<const int*>(ws);
  int* wsw = reinterpret_cast<int*>(ws);
  const int BS = *bsp;
#pragma unroll
  for (int c = 0; c < 6; ++c) {
    const int r = c*256 + tid;
    const int idx = b*ROWS + r;
    int asc = 0, dsc = 0;
#pragma unroll
    for (int jb = 0; jb < 4; ++jb) {
      asc += wsi[WS_ASCP + jb*NTOT + idx];
      dsc += wsi[WS_DSCP + jb*NTOT + idx];
    }
    out[NTOT + idx] = (float)(asc / BS + 1);
    wsw[WS_DESC + idx] = dsc;
    xs_l[dsc] = ws[WS_X + idx];
  }
  __syncthreads();
  // write xs to global (for k8b gather) and scan y = (ROWS-i) - xs
  const int base = tid * 6;
  float y[6], sum = 0.f;
#pragma unroll
  for (int u = 0; u < 6; ++u) {
    ws[WS_XS + b*ROWS + base + u] = xs_l[base + u];
    y[u] = (float)(ROWS - (base + u)) - xs_l[base + u];
    sum += y[u];
  }
  ts[tid] = sum;
  __syncthreads();
  for (int off = 1; off < 256; off <<= 1) {
    float v = ts[tid];
    if (tid >= off) v += ts[tid - off];
    __syncthreads();
    ts[tid] = v;
    __syncthreads();
  }
  float run = tid ? ts[tid - 1] : 0.f;
  float* S = ws + WS_S + b*SSTRIDE;
#pragma unroll
  for (int u = 0; u < 6; ++u) { S[base + u] = run; run += y[u]; }
  if (tid == 255) S[ROWS] = run;
  // pad tail with BIG so k8a needs no masking
#pragma unroll
  for (int u = 0; u < 6; ++u) S[ROWS + 1 + tid*6 + u] = BIGF;
}

// ---------------- K8a: chunk-partial minima of segment averages --------------
__global__ __launch_bounds__(256) void k8a(float* __restrict__ ws)
{
  const int bi = blockIdx.x;
  const int c = bi & 7, ib = (bi >> 3) % 6, b = bi / 48;
  const int tid = threadIdx.x;
  __shared__ float Sseg[448];
  __shared__ float invl[192];
  const float* S = ws + WS_S + b*SSTRIDE;
  const int ibase = ib*256;
  const int segbase = ibase + c*192 + 1;
  Sseg[tid] = S[segbase + tid];
  if (tid < 192) {
    Sseg[256 + tid] = S[segbase + 256 + tid];
    invl[tid] = 1.0f / (float)(c*192 + tid + 1);
  }
  __syncthreads();
  const int i = ibase + tid;
  const float Si = S[i];
  float gm = 3.0e38f;
#pragma unroll 8
  for (int k = 0; k < 192; ++k)
    gm = fminf(gm, (Sseg[tid + k] - Si) * invl[k]);
  ws[WS_GPART + (b*8 + c)*ROWS + i] = gm;
}

// --------- K8b: reduce partials, prefix-max (isotonic), final ranks ----------
__global__ __launch_bounds__(768) void k8b(float* __restrict__ ws,
                                           float* __restrict__ out)
{
  const int b = blockIdx.x, tid = threadIdx.x;
  __shared__ float g[ROWS];
  __shared__ float pm[768];
  for (int t = tid; t < ROWS; t += 768) {
    float gm = 3.0e38f;
#pragma unroll
    for (int c = 0; c < 8; ++c)
      gm = fminf(gm, ws[WS_GPART + (b*8 + c)*ROWS + t]);
    g[t] = gm;
  }
  __syncthreads();
  const float a = g[2*tid], cc = g[2*tid + 1];
  pm[tid] = fmaxf(a, cc);
  __syncthreads();
  for (int off = 1; off < 768; off <<= 1) {
    float v = pm[tid];
    if (tid >= off) v = fmaxf(v, pm[tid - off]);
    __syncthreads();
    pm[tid] = v;
    __syncthreads();
  }
  const float excl = tid ? pm[tid - 1] : -3.0e38f;
  const float i0 = fmaxf(excl, a);
  const float i1 = fmaxf(i0, cc);
  g[2*tid] = i0; g[2*tid + 1] = i1;
  __syncthreads();
  const float* xs = ws + WS_XS + b*ROWS;
  const int* desc = reinterpret_cast<const int*>(ws) + WS_DESC + b*ROWS;
  for (int t = tid; t < ROWS; t += 768) {
    const int dr = desc[t];
    out[b*ROWS + t] = xs[dr] + g[dr];
  }
}

extern "C" void kernel_launch(void* const* d_in, const int* in_sizes, int n_in,
                              void* d_out, int out_size, void* d_ws, size_t ws_size,
                              hipStream_t stream) {
  const float* table = (const float*)d_in[0];
  const float* w1  = (const float*)d_in[1];
  const float* b1  = (const float*)d_in[2];
  const float* w2  = (const float*)d_in[3];
  const float* b2  = (const float*)d_in[4];
  const float* mw  = (const float*)d_in[5];
  const float* mb  = (const float*)d_in[6];
  const float* dw1 = (const float*)d_in[7];
  const float* db1 = (const float*)d_in[8];
  const float* dw2 = (const float*)d_in[9];
  const float* db2 = (const float*)d_in[10];
  const int* labels = (const int*)d_in[11];
  const int* bsp    = (const int*)d_in[12];
  float* out = (float*)d_out;
  float* ws  = (float*)d_ws;

  k1_ae<<<96, 128, 0, stream>>>(table, w1, b1, w2, b2, mw, mb, dw1, db1, dw2, db2, ws);
  k2_cpart<<<48, 512, 0, stream>>>(labels, ws);
  k345<<<8, 256, 0, stream>>>(labels, ws, out);
  k6_count<<<192, 256, 0, stream>>>(ws, out);
  k67<<<8, 256, 0, stream>>>(bsp, ws, out);
  k8a<<<384, 256, 0, stream>>>(ws);
  k8b<<<8, 768, 0, stream>>>(ws, out);
}

// Round 3
// 77.682 us; speedup vs baseline: 3.4279x; 1.1141x over previous
//
#include <hip/hip_runtime.h>

#define BATCH 8
#define ROWS 1536
#define KCLS 32
#define NTOT (BATCH*ROWS)        // 12288
#define ELEMS (NTOT*16)          // 196608
#define SSTRIDE 3073             // padded prefix-sum stride per batch
#define BIGF 1.0e30f

// workspace layout (float offsets)
enum : int {
  WS_Z     = 0,                          // [8][1536][16]
  WS_X     = WS_Z + NTOT*16,             // [8][1536]
  WS_XS    = WS_X + NTOT,                // [8][1536]
  WS_S     = WS_XS + NTOT,               // [8][3073] padded
  WS_DESC  = WS_S + BATCH*SSTRIDE,       // [8][1536] int
  WS_ASCP  = WS_DESC + NTOT,             // [4][12288] int
  WS_DSCP  = WS_ASCP + 4*NTOT,           // [4][12288] int
  WS_GPART = WS_DSCP + 4*NTOT,           // [8][8][1536] (k8a) / [8][24][512] (cpart)
  WS_LOSSP = WS_GPART + BATCH*8*ROWS,    // [192]
};
#define WS_CPART WS_GPART   // disjoint lifetimes: cpart k1->k345, gpart k8a->k8b

// LDS weight layout (float offsets)
#define LW1  0
#define LB1  512
#define LW2  544
#define LB2  2592
#define LMW  2656
#define LMB  3680
#define LDW1 3696
#define LDB1 4208
#define LDW2 4240
#define LDB2 4752
#define LTOT 4768

// ---- K1: autoencoder + z + loss partials + fused center partials ----
__global__ __launch_bounds__(64, 1) void k1_ae(
    const float* __restrict__ table,
    const float* __restrict__ w1, const float* __restrict__ b1,
    const float* __restrict__ w2, const float* __restrict__ b2,
    const float* __restrict__ mw, const float* __restrict__ mb,
    const float* __restrict__ dw1, const float* __restrict__ db1,
    const float* __restrict__ dw2, const float* __restrict__ db2,
    const int* __restrict__ labels,
    float* __restrict__ ws)
{
  const int tid = threadIdx.x;
  const int blk = blockIdx.x;            // 0..191
  const int row = blk * 64 + tid;        // global row
  const int b   = blk / 24;              // batch
  const int ch  = blk % 24;              // 64-row chunk within batch

  __shared__ float wsh[LTOT];
  __shared__ float zsh[64 * 16];
  __shared__ int   lbl[64];

  // stage weights (float4, coalesced)
  {
    float4* d4 = reinterpret_cast<float4*>(wsh);
#define CPY(off, src, nf4) \
    { const float4* p = reinterpret_cast<const float4*>(src); \
      for (int t = tid; t < (nf4); t += 64) d4[(off)/4 + t] = p[t]; }
    CPY(LW1,  w1,  128) CPY(LB1,  b1,  8)  CPY(LW2,  w2,  512)
    CPY(LB2,  b2,  16)  CPY(LMW,  mw,  256) CPY(LMB,  mb,  4)
    CPY(LDW1, dw1, 128) CPY(LDB1, db1, 8)  CPY(LDW2, dw2, 128)
    CPY(LDB2, db2, 4)
#undef CPY
    lbl[tid] = labels[ch * 64 + tid];
  }
  __syncthreads();

  float x[16];
  {
    const float4* tp = reinterpret_cast<const float4*>(table + row * 16);
    float4 a0 = tp[0], a1 = tp[1], a2 = tp[2], a3 = tp[3];
    x[0]=a0.x; x[1]=a0.y; x[2]=a0.z; x[3]=a0.w;
    x[4]=a1.x; x[5]=a1.y; x[6]=a1.z; x[7]=a1.w;
    x[8]=a2.x; x[9]=a2.y; x[10]=a2.z; x[11]=a2.w;
    x[12]=a3.x; x[13]=a3.y; x[14]=a3.z; x[15]=a3.w;
  }

  float h1[32];
#pragma unroll
  for (int j = 0; j < 32; ++j) h1[j] = wsh[LB1 + j];
#pragma unroll 4
  for (int i = 0; i < 16; ++i) {
    const float xi = x[i];
#pragma unroll
    for (int j = 0; j < 32; ++j) h1[j] = fmaf(xi, wsh[LW1 + i*32 + j], h1[j]);
  }
#pragma unroll
  for (int j = 0; j < 32; ++j) h1[j] = fmaxf(h1[j], 0.f);

  float h2[64];
#pragma unroll
  for (int j = 0; j < 64; ++j) h2[j] = wsh[LB2 + j];
#pragma unroll 2
  for (int i = 0; i < 32; ++i) {
    const float hi = h1[i];
#pragma unroll
    for (int j = 0; j < 64; ++j) h2[j] = fmaf(hi, wsh[LW2 + i*64 + j], h2[j]);
  }
#pragma unroll
  for (int j = 0; j < 64; ++j) h2[j] = fmaxf(h2[j], 0.f);

  float z[16];
#pragma unroll
  for (int j = 0; j < 16; ++j) z[j] = wsh[LMB + j];
#pragma unroll 8
  for (int i = 0; i < 64; ++i) {
    const float hi = h2[i];
#pragma unroll
    for (int j = 0; j < 16; ++j) z[j] = fmaf(hi, wsh[LMW + i*16 + j], z[j]);
  }
  {
    float4* zp = reinterpret_cast<float4*>(ws + WS_Z + row * 16);
    zp[0] = make_float4(z[0], z[1], z[2], z[3]);
    zp[1] = make_float4(z[4], z[5], z[6], z[7]);
    zp[2] = make_float4(z[8], z[9], z[10], z[11]);
    zp[3] = make_float4(z[12], z[13], z[14], z[15]);
#pragma unroll
    for (int j = 0; j < 16; ++j) zsh[tid*16 + j] = z[j];
  }

  float r1[32];
#pragma unroll
  for (int j = 0; j < 32; ++j) r1[j] = wsh[LDB1 + j];
#pragma unroll 4
  for (int i = 0; i < 16; ++i) {
    const float zi = z[i];
#pragma unroll
    for (int j = 0; j < 32; ++j) r1[j] = fmaf(zi, wsh[LDW1 + i*32 + j], r1[j]);
  }
#pragma unroll
  for (int j = 0; j < 32; ++j) r1[j] = fmaxf(r1[j], 0.f);

  float rec[16];
#pragma unroll
  for (int j = 0; j < 16; ++j) rec[j] = wsh[LDB2 + j];
#pragma unroll 8
  for (int i = 0; i < 32; ++i) {
    const float ri = r1[i];
#pragma unroll
    for (int j = 0; j < 16; ++j) rec[j] = fmaf(ri, wsh[LDW2 + i*16 + j], rec[j]);
  }
  float ls = 0.f;
#pragma unroll
  for (int j = 0; j < 16; ++j) {
    float d = fmaxf(rec[j], 0.f) - x[j];
    ls = fmaf(d, d, ls);
  }
  for (int off = 32; off > 0; off >>= 1) ls += __shfl_down(ls, off);
  if (tid == 0) ws[WS_LOSSP + blk] = ls;

  // fused center partials over this 64-row chunk
  __syncthreads();
  float acc[8] = {0.f,0.f,0.f,0.f,0.f,0.f,0.f,0.f};
  for (int rr = 0; rr < 64; ++rr) {
    const int lb = lbl[rr];
#pragma unroll
    for (int p = 0; p < 8; ++p) {
      const int idx = tid*8 + p;
      acc[p] += (lb == (idx >> 4)) ? zsh[rr*16 + (idx & 15)] : 0.f;
    }
  }
#pragma unroll
  for (int p = 0; p < 8; ++p)
    ws[WS_CPART + (b*24 + ch)*512 + tid*8 + p] = acc[p];
}

// ---- K345: centers finalize + loss + d2 + normalizations + scores + x ------
__global__ __launch_bounds__(256) void k345(const int* __restrict__ labels,
                                            float* __restrict__ ws,
                                            float* __restrict__ out)
{
  const int b = blockIdx.x;
  const int tid = threadIdx.x;
  __shared__ int cnt[KCLS];
  __shared__ float cent[512];
  __shared__ float rmn[256], rmx[256];
  __shared__ int lbl_l[ROWS];

  // loss reduction (all blocks compute, block 0 writes)
  rmn[tid] = (tid < 192) ? ws[WS_LOSSP + tid] : 0.f;
  if (tid < KCLS) cnt[tid] = 0;
  __syncthreads();
  for (int off = 128; off > 0; off >>= 1) {
    if (tid < off) rmn[tid] += rmn[tid + off];
    __syncthreads();
  }
  if (b == 0 && tid == 0) out[3*NTOT] = rmn[0] / (float)ELEMS;

#pragma unroll
  for (int c = 0; c < 6; ++c) {
    int lb = labels[c*256 + tid];
    lbl_l[c*256 + tid] = lb;
    atomicAdd(&cnt[lb], 1);
  }
  __syncthreads();
#pragma unroll
  for (int e = tid; e < 512; e += 256) {
    float s = 0.f;
#pragma unroll
    for (int c = 0; c < 24; ++c) s += ws[WS_CPART + (b*24 + c)*512 + e];
    const int cn = cnt[e >> 4] > 1 ? cnt[e >> 4] : 1;
    cent[e] = s / (float)cn;
  }
  __syncthreads();

  // d2 per row (6 rows/thread), block min/max
  float d2v[6];
  float tmn = 3.0e38f, tmx = -3.0e38f;
#pragma unroll
  for (int c = 0; c < 6; ++c) {
    const int r = c*256 + tid;
    const int lb = lbl_l[r];
    const float4* zp = reinterpret_cast<const float4*>(ws + WS_Z + (b*ROWS + r)*16);
    const float4* cp = reinterpret_cast<const float4*>(&cent[lb*16]);
    float s = 0.f;
#pragma unroll
    for (int q = 0; q < 4; ++q) {
      float4 zv = zp[q], cv = cp[q];
      float d0 = zv.x - cv.x, d1 = zv.y - cv.y, d2_ = zv.z - cv.z, d3 = zv.w - cv.w;
      s += d0*d0 + d1*d1 + d2_*d2_ + d3*d3;
    }
    d2v[c] = s / 16.f;
    tmn = fminf(tmn, d2v[c]); tmx = fmaxf(tmx, d2v[c]);
  }
  rmn[tid] = tmn; rmx[tid] = tmx;
  __syncthreads();
  for (int off = 128; off > 0; off >>= 1) {
    if (tid < off) {
      rmn[tid] = fminf(rmn[tid], rmn[tid + off]);
      rmx[tid] = fmaxf(rmx[tid], rmx[tid + off]);
    }
    __syncthreads();
  }
  const float mn = rmn[0], mx = rmx[0];
  __syncthreads();

  float sv[6];
  tmn = 3.0e38f; tmx = -3.0e38f;
#pragma unroll
  for (int c = 0; c < 6; ++c) {
    const int r = c*256 + tid;
    float sc = (d2v[c] - mn) / (mx - mn) + (float)lbl_l[r];
    sv[c] = sc;
    out[2*NTOT + b*ROWS + r] = sc;
    tmn = fminf(tmn, sc); tmx = fmaxf(tmx, sc);
  }
  rmn[tid] = tmn; rmx[tid] = tmx;
  __syncthreads();
  for (int off = 128; off > 0; off >>= 1) {
    if (tid < off) {
      rmn[tid] = fminf(rmn[tid], rmn[tid + off]);
      rmx[tid] = fmaxf(rmx[tid], rmx[tid + off]);
    }
    __syncthreads();
  }
  const float smn = rmn[0], smx = rmx[0];
#pragma unroll
  for (int c = 0; c < 6; ++c) {
    const int r = c*256 + tid;
    float scl = (sv[c] - smn) / (smx - smn) * 8.0f;
    ws[WS_X + b*ROWS + r] = scl / 0.01f;
  }
}

// ---------------- K6: partial stable rank counts (192 blocks) ----------------
__global__ __launch_bounds__(256) void k6_count(float* __restrict__ ws,
                                                const float* __restrict__ out)
{
  const int bi = blockIdx.x;
  const int jb = bi & 3, rb = (bi >> 2) % 6, b = bi / 24;
  const int tid = threadIdx.x;
  __shared__ float4 sld[96], xld[96];
  {
    float* sf = reinterpret_cast<float*>(sld);
    float* xf = reinterpret_cast<float*>(xld);
    const int base = b*ROWS + jb*384;
    sf[tid] = out[2*NTOT + base + tid];
    xf[tid] = ws[WS_X + base + tid];
    if (tid < 128) {
      sf[256 + tid] = out[2*NTOT + base + 256 + tid];
      xf[256 + tid] = ws[WS_X + base + 256 + tid];
    }
  }
  __syncthreads();
  const int r = rb*256 + tid;
  const float si = out[2*NTOT + b*ROWS + r];
  const float xi = ws[WS_X + b*ROWS + r];
  int asc = 0, dsc = 0;
  const int j0 = jb*384;
#pragma unroll 4
  for (int kk = 0; kk < 96; ++kk) {
    const float4 s4 = sld[kk];
    const float4 x4 = xld[kk];
    const int j = j0 + kk*4;
    asc += (s4.x < si || (s4.x == si && j   < r)) ? 1 : 0;
    asc += (s4.y < si || (s4.y == si && j+1 < r)) ? 1 : 0;
    asc += (s4.z < si || (s4.z == si && j+2 < r)) ? 1 : 0;
    asc += (s4.w < si || (s4.w == si && j+3 < r)) ? 1 : 0;
    dsc += (x4.x > xi || (x4.x == xi && j   < r)) ? 1 : 0;
    dsc += (x4.y > xi || (x4.y == xi && j+1 < r)) ? 1 : 0;
    dsc += (x4.z > xi || (x4.z == xi && j+2 < r)) ? 1 : 0;
    dsc += (x4.w > xi || (x4.w == xi && j+3 < r)) ? 1 : 0;
  }
  int* wsi = reinterpret_cast<int*>(ws);
  wsi[WS_ASCP + jb*NTOT + b*ROWS + r] = asc;
  wsi[WS_DSCP + jb*NTOT + b*ROWS + r] = dsc;
}

// ------- K67: finalize counts -> rank_idx, scatter xs, prefix-sum S ---------
__global__ __launch_bounds__(256) void k67(const int* __restrict__ bsp,
                                           float* __restrict__ ws,
                                           float* __restrict__ out)
{
  const int b = blockIdx.x, tid = threadIdx.x;
  __shared__ float xs_l[ROWS];
  __shared__ float ts[256];
  const int* wsi = reinterpret_cast<const int*>(ws);
  int* wsw = reinterpret_cast<int*>(ws);
  const int BS = *bsp;
#pragma unroll
  for (int c = 0; c < 6; ++c) {
    const int r = c*256 + tid;
    const int idx = b*ROWS + r;
    int asc = 0, dsc = 0;
#pragma unroll
    for (int jb = 0; jb < 4; ++jb) {
      asc += wsi[WS_ASCP + jb*NTOT + idx];
      dsc += wsi[WS_DSCP + jb*NTOT + idx];
    }
    out[NTOT + idx] = (float)(asc / BS + 1);
    wsw[WS_DESC + idx] = dsc;
    xs_l[dsc] = ws[WS_X + idx];
  }
  __syncthreads();
  const int base = tid * 6;
  float y[6], sum = 0.f;
#pragma unroll
  for (int u = 0; u < 6; ++u) {
    ws[WS_XS + b*ROWS + base + u] = xs_l[base + u];
    y[u] = (float)(ROWS - (base + u)) - xs_l[base + u];
    sum += y[u];
  }
  ts[tid] = sum;
  __syncthreads();
  for (int off = 1; off < 256; off <<= 1) {
    float v = ts[tid];
    if (tid >= off) v += ts[tid - off];
    __syncthreads();
    ts[tid] = v;
    __syncthreads();
  }
  float run = tid ? ts[tid - 1] : 0.f;
  float* S = ws + WS_S + b*SSTRIDE;
#pragma unroll
  for (int u = 0; u < 6; ++u) { S[base + u] = run; run += y[u]; }
  if (tid == 255) S[ROWS] = run;
#pragma unroll
  for (int u = 0; u < 6; ++u) S[ROWS + 1 + tid*6 + u] = BIGF;
}

// ---------------- K8a: chunk-partial minima of segment averages --------------
__global__ __launch_bounds__(256) void k8a(float* __restrict__ ws)
{
  const int bi = blockIdx.x;
  const int c = bi & 7, ib = (bi >> 3) % 6, b = bi / 48;
  const int tid = threadIdx.x;
  __shared__ float Sseg[448];
  __shared__ float invl[192];
  const float* S = ws + WS_S + b*SSTRIDE;
  const int ibase = ib*256;
  const int segbase = ibase + c*192 + 1;
  Sseg[tid] = S[segbase + tid];
  if (tid < 192) {
    Sseg[256 + tid] = S[segbase + 256 + tid];
    invl[tid] = 1.0f / (float)(c*192 + tid + 1);
  }
  __syncthreads();
  const int i = ibase + tid;
  const float Si = S[i];
  float gm = 3.0e38f;
#pragma unroll 8
  for (int k = 0; k < 192; ++k)
    gm = fminf(gm, (Sseg[tid + k] - Si) * invl[k]);
  ws[WS_GPART + (b*8 + c)*ROWS + i] = gm;
}

// --------- K8b: reduce partials, prefix-max (isotonic), final ranks ----------
__global__ __launch_bounds__(768) void k8b(float* __restrict__ ws,
                                           float* __restrict__ out)
{
  const int b = blockIdx.x, tid = threadIdx.x;
  __shared__ float g[ROWS];
  __shared__ float pm[768];
  for (int t = tid; t < ROWS; t += 768) {
    float gm = 3.0e38f;
#pragma unroll
    for (int c = 0; c < 8; ++c)
      gm = fminf(gm, ws[WS_GPART + (b*8 + c)*ROWS + t]);
    g[t] = gm;
  }
  __syncthreads();
  const float a = g[2*tid], cc = g[2*tid + 1];
  pm[tid] = fmaxf(a, cc);
  __syncthreads();
  for (int off = 1; off < 768; off <<= 1) {
    float v = pm[tid];
    if (tid >= off) v = fmaxf(v, pm[tid - off]);
    __syncthreads();
    pm[tid] = v;
    __syncthreads();
  }
  const float excl = tid ? pm[tid - 1] : -3.0e38f;
  const float i0 = fmaxf(excl, a);
  const float i1 = fmaxf(i0, cc);
  g[2*tid] = i0; g[2*tid + 1] = i1;
  __syncthreads();
  const float* xs = ws + WS_XS + b*ROWS;
  const int* desc = reinterpret_cast<const int*>(ws) + WS_DESC + b*ROWS;
  for (int t = tid; t < ROWS; t += 768) {
    const int dr = desc[t];
    out[b*ROWS + t] = xs[dr] + g[dr];
  }
}

extern "C" void kernel_launch(void* const* d_in, const int* in_sizes, int n_in,
                              void* d_out, int out_size, void* d_ws, size_t ws_size,
                              hipStream_t stream) {
  const float* table = (const float*)d_in[0];
  const float* w1  = (const float*)d_in[1];
  const float* b1  = (const float*)d_in[2];
  const float* w2  = (const float*)d_in[3];
  const float* b2  = (const float*)d_in[4];
  const float* mw  = (const float*)d_in[5];
  const float* mb  = (const float*)d_in[6];
  const float* dw1 = (const float*)d_in[7];
  const float* db1 = (const float*)d_in[8];
  const float* dw2 = (const float*)d_in[9];
  const float* db2 = (const float*)d_in[10];
  const int* labels = (const int*)d_in[11];
  const int* bsp    = (const int*)d_in[12];
  float* out = (float*)d_out;
  float* ws  = (float*)d_ws;

  k1_ae<<<192, 64, 0, stream>>>(table, w1, b1, w2, b2, mw, mb, dw1, db1, dw2, db2, labels, ws);
  k345<<<8, 256, 0, stream>>>(labels, ws, out);
  k6_count<<<192, 256, 0, stream>>>(ws, out);
  k67<<<8, 256, 0, stream>>>(bsp, ws, out);
  k8a<<<384, 256, 0, stream>>>(ws);
  k8b<<<8, 768, 0, stream>>>(ws, out);
}